// Round 17
// baseline (106.755 us; speedup 1.0000x reference)
//
#include <hip/hip_runtime.h>
#include <hip/hip_cooperative_groups.h>

namespace cg = cooperative_groups;

#define NB   384
#define ND   256
#define EPSF 1e-6f
#define NBIN 384

// ws layout (floats):
#define WF_OFF   0                        // wf[4] = tw_t / count_t
#define PART_OFF 16                       // partial[384]
#define ETP_OFF  1024                     // uint2[64][384]: bf16-packed emb^T

__device__ __forceinline__ unsigned bf16rne(float f) {
    const unsigned b = __float_as_uint(f);
    return (b + 0x7FFFu + ((b >> 16) & 1u)) >> 16;   // round-nearest-even
}

// ---------------------------------------------------------------------------
// Single cooperative kernel, 384 blocks x 384 threads (all co-resident:
// 6 waves + ~13KB LDS per block).
//  Phase A (blocks 0..95): 32x32 LDS-tile transpose -> bf16 ETP (eps folded);
//          block 0 additionally: wf[t] = tw_t / count_t (analytic counts).
//  grid.sync()  -- device-scope release/acquire: ETP/wf visible cross-XCD
//  Phase B (block i == row i): R15's verified loss body:
//    P1 d_p from bf16 ETP (coalesced 8B lane loads; e_i wave-uniform scalar)
//    P2 min(excl self)/max -> integer bins-per-unit S (bin(d+1)==bin(d)+S)
//    P3 384-bin histogram -> shfl prefix -> counting scatter of rank packs
//    P4 ballot cumulative-rank masks (bank-padded tables)
//    P5 j-role + k-role counts at the same bin-boundary cuts
//    -> partial[i] (plain store)
//  grid.sync()
//  Phase C (block 0): fold 384 partials -> out[0].
// ---------------------------------------------------------------------------
__global__ __launch_bounds__(NB) void fused_kernel(
    const float* __restrict__ emb,
    const float* __restrict__ tw,
    const int*   __restrict__ rank,
    float*       __restrict__ ws,
    float*       __restrict__ out)
{
    __shared__ float    tt[32][33];
    __shared__ unsigned hist20[20];
    __shared__ unsigned hist[NBIN];
    __shared__ unsigned offs[NBIN + 1];
    __shared__ unsigned curs[NBIN];
    __shared__ unsigned srk[NB];
    __shared__ unsigned long long cm[7][17];   // row 6 zero; padded rows
    __shared__ unsigned cumtab[7][17];         // row 6 totals; padded rows
    __shared__ unsigned wtot[6];
    __shared__ float    mmx[12];
    __shared__ float    sprm[2];
    __shared__ float    wfl[4];
    __shared__ float    red[6];

    const int p   = threadIdx.x;       // 0..383
    const int bid = blockIdx.x;        // 0..383
    const int wv  = p >> 6;            // 0..5
    cg::grid_group grid = cg::this_grid();

    // ---------------- Phase A: transpose+pack (blocks 0..95) ----------------
    if (bid < 96) {
        const int dt = bid & 7;        // 8 d-tiles of 32
        const int jt = bid >> 3;       // 12 j-tiles of 32
        if (p < 256) {
            const int c  = p & 31;
            const int r8 = p >> 5;
            #pragma unroll
            for (int u = 0; u < 4; ++u) {
                const int j = jt * 32 + r8 + u * 8;
                const int d = dt * 32 + c;
                tt[r8 + u * 8][c] = emb[(size_t)j * ND + d];   // coalesced
            }
        }
        __syncthreads();
        if (p < 256) {
            const int jloc = p & 31;
            const int gl   = p >> 5;   // 0..7
            const float v0 = tt[jloc][gl * 4 + 0] - EPSF;
            const float v1 = tt[jloc][gl * 4 + 1] - EPSF;
            const float v2 = tt[jloc][gl * 4 + 2] - EPSF;
            const float v3 = tt[jloc][gl * 4 + 3] - EPSF;
            uint2 o;
            o.x = bf16rne(v0) | (bf16rne(v1) << 16);
            o.y = bf16rne(v2) | (bf16rne(v3) << 16);
            reinterpret_cast<uint2*>(ws + ETP_OFF)
                [(size_t)(dt * 8 + gl) * NB + jt * 32 + jloc] = o;
        }
    }
    if (bid == 0) {
        if (p < 20) hist20[p] = 0u;
        __syncthreads();
        for (int e = p; e < NB * 4; e += NB)
            atomicAdd(&hist20[(e & 3) * 5 + rank[e]], 1u);
        __syncthreads();
        if (p < 4) {
            double cnt = 0.0;
            unsigned below = 0;
            #pragma unroll
            for (int v = 0; v < 5; ++v) {
                unsigned hv = hist20[p * 5 + v];
                unsigned above = (unsigned)NB - below - hv;
                cnt += (double)hv * (double)below * (double)above;
                below += hv;
            }
            ws[WF_OFF + p] = (cnt > 0.0) ? (float)((double)tw[p] / cnt) : 0.f;
        }
    }

    grid.sync();                       // ETP + wf visible to all blocks

    // ---------------- Phase B: per-row loss (block == row) ------------------
    const int bi = bid;

    if (p < 4)  wfl[p] = ws[WF_OFF + p];
    if (p < 17) cm[6][p] = 0ull;
    hist[p] = 0u;

    // P1: distance (bf16 ej from ETP, f32 ei via scalar path)
    const uint2* etp = reinterpret_cast<const uint2*>(ws + ETP_OFF);
    const float* ei  = emb + (size_t)bi * ND;     // uniform -> s_load
    float acc = 0.f;
    for (int g0 = 0; g0 < 64; g0 += 8) {          // 8 batches of 8 loads
        uint2 l[8];
        #pragma unroll
        for (int u = 0; u < 8; ++u)
            l[u] = etp[(size_t)(g0 + u) * NB + p];
        #pragma unroll
        for (int u = 0; u < 8; ++u) {
            const int dd = (g0 + u) * 4;
            const float j0 = __uint_as_float(l[u].x << 16);
            const float j1 = __uint_as_float(l[u].x & 0xFFFF0000u);
            const float j2 = __uint_as_float(l[u].y << 16);
            const float j3 = __uint_as_float(l[u].y & 0xFFFF0000u);
            const float t0 = ei[dd + 0] - j0;
            const float t1 = ei[dd + 1] - j1;
            const float t2 = ei[dd + 2] - j2;
            const float t3 = ei[dd + 3] - j3;
            acc = fmaf(t0, t0, acc);
            acc = fmaf(t1, t1, acc);
            acc = fmaf(t2, t2, acc);
            acc = fmaf(t3, t3, acc);
        }
    }
    const float d = sqrtf(acc);

    // P2: min (excluding self) / max -> integer scale
    float dl = (p == bi) ? 3.0e38f : d;
    float dh = d;
    #pragma unroll
    for (int off = 32; off > 0; off >>= 1) {
        dl = fminf(dl, __shfl_xor(dl, off, 64));
        dh = fmaxf(dh, __shfl_xor(dh, off, 64));
    }
    if ((p & 63) == 0) { mmx[wv] = dl; mmx[6 + wv] = dh; }
    __syncthreads();
    if (p == 0) {
        float mn = mmx[0], mx = mmx[6];
        #pragma unroll
        for (int w = 1; w < 6; ++w) {
            mn = fminf(mn, mmx[w]);
            mx = fmaxf(mx, mmx[6 + w]);
        }
        int S = (int)(383.0f / (mx - mn + 1.0f));
        if (S < 1) S = 1;
        sprm[0] = mn;
        sprm[1] = (float)S;
    }
    __syncthreads();
    const float dmin   = sprm[0];
    const float scaleF = sprm[1];
    const int   S      = (int)scaleF;

    // P3a: histogram (self clamps to bin 0; rank strictness excludes it)
    int q = (int)((d - dmin) * scaleF);
    if (q < 0) q = 0;
    if (q > NBIN - 1) q = NBIN - 1;
    atomicAdd(&hist[q], 1u);
    const int4 r4 = *reinterpret_cast<const int4*>(rank + p * 4);
    const unsigned rpk = (unsigned)r4.x | ((unsigned)r4.y << 8) |
                         ((unsigned)r4.z << 16) | ((unsigned)r4.w << 24);
    __syncthreads();

    // P3b: exclusive prefix over 384 bins
    const unsigned h = hist[p];
    unsigned inc = h;
    #pragma unroll
    for (int s = 1; s < 64; s <<= 1) {
        const unsigned o = __shfl_up(inc, s, 64);
        if ((p & 63) >= s) inc += o;
    }
    if ((p & 63) == 63) wtot[wv] = inc;
    __syncthreads();
    unsigned woff = 0;
    for (int w = 0; w < wv; ++w) woff += wtot[w];
    const unsigned excl = woff + inc - h;
    offs[p] = excl;
    curs[p] = excl;
    if (p == NBIN - 1) offs[NBIN] = excl + h;   // == NB
    __syncthreads();

    // P3c: counting scatter into d-grouped order
    const unsigned pos = atomicAdd(&curs[q], 1u);
    srk[pos] = rpk;
    __syncthreads();

    // P4: ballot cumulative-rank masks
    const unsigned rsv = srk[p];
    #pragma unroll
    for (int t = 0; t < 4; ++t) {
        const unsigned rt = (rsv >> (8 * t)) & 0xFFu;
        #pragma unroll
        for (int w = 0; w < 4; ++w) {
            const unsigned long long m = __ballot(rt <= (unsigned)w);
            if ((p & 63) == 0) cm[wv][t * 4 + w] = m;
        }
    }
    __syncthreads();
    if (p < 16) {
        unsigned c = 0;
        #pragma unroll
        for (int w2 = 0; w2 < 6; ++w2) {
            cumtab[w2][p] = c;
            c += (unsigned)__popcll(cm[w2][p]);
        }
        cumtab[6][p] = c;                       // grand totals
    }
    __syncthreads();

    // P5: contribution (both roles)
    const float thr = d + 1.0f;
    const int jidx = (q + S > NBIN) ? NBIN : (q + S);
    const int kidx = (q - S + 1 < 0) ? 0 : (q - S + 1);
    const unsigned P = offs[jidx];     // j-role partners: pos <  P
    const unsigned L = offs[kidx];     // k-role partners: pos >= L
    const int Pwv = (int)(P >> 6), Lwv = (int)(L >> 6);
    const unsigned long long Pmask = (1ull << (P & 63)) - 1ull;
    const unsigned long long Lmask = (1ull << (L & 63)) - 1ull;

    const int4 ri4 = *reinterpret_cast<const int4*>(rank + bi * 4);
    const unsigned rip = (unsigned)ri4.x | ((unsigned)ri4.y << 8) |
                         ((unsigned)ri4.z << 16) | ((unsigned)ri4.w << 24);

    float jacc = 0.f, kacc = 0.f;
    #pragma unroll
    for (int t = 0; t < 4; ++t) {
        const int ri = (int)((rip >> (8 * t)) & 0xFFu);
        const int ro = (int)((rpk >> (8 * t)) & 0xFFu);
        const float wt = wfl[t];
        if (ro > 0 && ro < ri) {                       // j-role
            const int w = t * 4 + (ro - 1);
            const unsigned N = cumtab[Pwv][w] +
                               (unsigned)__popcll(cm[Pwv][w] & Pmask);
            jacc += wt * (float)N;
        }
        if (ro + 1 < ri) {                             // k-role
            const int wh = t * 4 + (ri - 1);
            const int wl = t * 4 + ro;
            const unsigned cLh = cumtab[Lwv][wh] +
                                 (unsigned)__popcll(cm[Lwv][wh] & Lmask);
            const unsigned cLl = cumtab[Lwv][wl] +
                                 (unsigned)__popcll(cm[Lwv][wl] & Lmask);
            const unsigned C = (cumtab[6][wh] - cLh) - (cumtab[6][wl] - cLl);
            kacc += wt * (float)C;
        }
    }
    float contrib = jacc * thr - kacc * d;

    // block reduction -> partial[bi]
    #pragma unroll
    for (int off = 32; off > 0; off >>= 1)
        contrib += __shfl_down(contrib, off);
    if ((p & 63) == 0) red[wv] = contrib;
    __syncthreads();
    if (p == 0) {
        float s = 0.f;
        #pragma unroll
        for (int w = 0; w < 6; ++w) s += red[w];
        ws[PART_OFF + bi] = s;
    }

    grid.sync();                       // partials visible device-wide

    // ---------------- Phase C: block 0 folds partials -> out ---------------
    if (bid == 0) {
        float v = ws[PART_OFF + p];
        #pragma unroll
        for (int off = 32; off > 0; off >>= 1)
            v += __shfl_down(v, off);
        if ((p & 63) == 0) red[wv] = v;
        __syncthreads();
        if (p == 0) {
            float s = 0.f;
            #pragma unroll
            for (int w = 0; w < 6; ++w) s += red[w];
            out[0] = s;
        }
    }
}

extern "C" void kernel_launch(void* const* d_in, const int* in_sizes, int n_in,
                              void* d_out, int out_size, void* d_ws, size_t ws_size,
                              hipStream_t stream)
{
    (void)in_sizes; (void)n_in; (void)out_size; (void)ws_size;
    const float* emb  = (const float*)d_in[0];
    const float* tw   = (const float*)d_in[1];
    const int*   rank = (const int*)d_in[2];
    float* ws  = (float*)d_ws;
    float* out = (float*)d_out;

    void* args[] = { (void*)&emb, (void*)&tw, (void*)&rank,
                     (void*)&ws, (void*)&out };
    hipLaunchCooperativeKernel(reinterpret_cast<void*>(fused_kernel),
                               dim3(NB), dim3(NB), args, 0, stream);
}

// Round 18
// 22.034 us; speedup vs baseline: 4.8451x; 4.8451x over previous
//
#include <hip/hip_runtime.h>

#define NB   384
#define ND   256
#define EPSF 1e-6f
#define NBIN 384
#define SENT 0xFFFFFFFFu                  // NaN bit pattern: finite sums never match

// ws layout (floats):
#define WF_OFF   0                        // wf[4] = tw_t / count_t
#define PART_OFF 16                       // partial[384] (prep sets sentinel)
#define ETP_OFF  1024                     // uint2[64][384]: bf16-packed emb^T

__device__ __forceinline__ unsigned bf16rne(float f) {
    const unsigned b = __float_as_uint(f);
    return (b + 0x7FFFu + ((b >> 16) & 1u)) >> 16;   // round-nearest-even
}

// ---------------------------------------------------------------------------
// K1: transpose emb -> ETP[g][j] = bf16x4 of dims {4g..4g+3} of (e_j - eps).
// 32x32 LDS tile per block. Block 0: wf[t] = tw_t / count_t (analytic counts).
// Block 1: reset partial[] to sentinel (stream order makes it visible to K2).
// ---------------------------------------------------------------------------
__global__ __launch_bounds__(256) void prep_kernel(
    const float* __restrict__ emb,
    const float* __restrict__ tw,
    const int*   __restrict__ rank,
    float* __restrict__ ws)
{
    __shared__ float    t[32][33];
    __shared__ unsigned hist[20];

    const int tid = threadIdx.x;
    const int dt  = blockIdx.x & 7;      // 8 d-tiles of 32
    const int jt  = blockIdx.x >> 3;     // 12 j-tiles of 32
    const int c   = tid & 31;
    const int r8  = tid >> 5;

    #pragma unroll
    for (int p = 0; p < 4; ++p) {
        const int j = jt * 32 + r8 + p * 8;
        const int d = dt * 32 + c;
        t[r8 + p * 8][c] = emb[(size_t)j * ND + d];    // coalesced
    }
    __syncthreads();

    // pack 4 consecutive dims of one j into uint2 (bf16 x4), eps folded
    const int jloc = tid & 31;
    const int gl   = tid >> 5;           // 0..7 (d-group within tile)
    const float v0 = t[jloc][gl * 4 + 0] - EPSF;
    const float v1 = t[jloc][gl * 4 + 1] - EPSF;
    const float v2 = t[jloc][gl * 4 + 2] - EPSF;
    const float v3 = t[jloc][gl * 4 + 3] - EPSF;
    uint2 o;
    o.x = bf16rne(v0) | (bf16rne(v1) << 16);
    o.y = bf16rne(v2) | (bf16rne(v3) << 16);
    uint2* etp = reinterpret_cast<uint2*>(ws + ETP_OFF);
    etp[(size_t)(dt * 8 + gl) * NB + jt * 32 + jloc] = o;   // coalesced 8B

    if (blockIdx.x == 0) {
        if (tid < 20) hist[tid] = 0u;
        __syncthreads();
        for (int e = tid; e < NB * 4; e += 256)
            atomicAdd(&hist[(e & 3) * 5 + rank[e]], 1u);
        __syncthreads();
        if (tid < 4) {
            double cnt = 0.0;
            unsigned below = 0;
            #pragma unroll
            for (int v = 0; v < 5; ++v) {
                unsigned hv = hist[tid * 5 + v];
                unsigned above = (unsigned)NB - below - hv;
                cnt += (double)hv * (double)below * (double)above;
                below += hv;
            }
            ws[WF_OFF + tid] = (cnt > 0.0) ? (float)((double)tw[tid] / cnt) : 0.f;
        }
    }
    if (blockIdx.x == 1) {
        unsigned* part = reinterpret_cast<unsigned*>(ws + PART_OFF);
        for (int p = tid; p < NB; p += 256) part[p] = SENT;
    }
}

// ---------------------------------------------------------------------------
// K2: one block per row i, 384 threads (1:1 with elements, no pad lanes).
//  P1: d_p from bf16 ETP (coalesced 8B); e_i wave-uniform -> scalar path
//  P2: min (excl self) / max -> integer bins-per-unit S (bin(d+1)=bin(d)+S)
//  P3: 384-bin histogram -> shfl prefix scan -> counting scatter of rank packs
//  P4: ballot cumulative-rank masks over d-grouped order (bank-padded tables)
//  P5: j-role + k-role counting at the same bin-boundary cuts
//  Tail: release-store own partial (independent lines, no RMW storm);
//        block NB-1 acquire-polls all 384 slots past sentinel, folds -> out.
// ---------------------------------------------------------------------------
__global__ __launch_bounds__(NB) void loss_kernel(
    const float* __restrict__ emb,
    const uint2* __restrict__ etp,
    const int*   __restrict__ rank,
    const float* __restrict__ wf,
    unsigned*    __restrict__ partial,
    float*       __restrict__ out)
{
    __shared__ unsigned hist[NBIN];
    __shared__ unsigned offs[NBIN + 1];
    __shared__ unsigned curs[NBIN];
    __shared__ unsigned srk[NB];
    __shared__ unsigned long long cm[7][17];   // row 6 zero; padded rows
    __shared__ unsigned cumtab[7][17];         // row 6 totals; padded rows
    __shared__ unsigned wtot[6];
    __shared__ float    mmx[12];
    __shared__ float    sprm[2];
    __shared__ float    wfl[4];
    __shared__ float    red[6];

    const int p  = threadIdx.x;        // 0..383
    const int bi = blockIdx.x;         // row
    const int wv = p >> 6;             // 0..5

    if (p < 4)  wfl[p] = wf[p];
    if (p < 17) cm[6][p] = 0ull;
    hist[p] = 0u;

    // P1: distance (bf16 ej from ETP, f32 ei via scalar path)
    const float* ei = emb + (size_t)bi * ND;      // uniform -> s_load
    float acc = 0.f;
    for (int g0 = 0; g0 < 64; g0 += 8) {          // 8 batches of 8 loads
        uint2 l[8];
        #pragma unroll
        for (int u = 0; u < 8; ++u)
            l[u] = etp[(size_t)(g0 + u) * NB + p];
        #pragma unroll
        for (int u = 0; u < 8; ++u) {
            const int dd = (g0 + u) * 4;
            const float j0 = __uint_as_float(l[u].x << 16);
            const float j1 = __uint_as_float(l[u].x & 0xFFFF0000u);
            const float j2 = __uint_as_float(l[u].y << 16);
            const float j3 = __uint_as_float(l[u].y & 0xFFFF0000u);
            const float t0 = ei[dd + 0] - j0;
            const float t1 = ei[dd + 1] - j1;
            const float t2 = ei[dd + 2] - j2;
            const float t3 = ei[dd + 3] - j3;
            acc = fmaf(t0, t0, acc);
            acc = fmaf(t1, t1, acc);
            acc = fmaf(t2, t2, acc);
            acc = fmaf(t3, t3, acc);
        }
    }
    const float d = sqrtf(acc);

    // P2: min (excluding self) / max -> integer scale
    float dl = (p == bi) ? 3.0e38f : d;
    float dh = d;
    #pragma unroll
    for (int off = 32; off > 0; off >>= 1) {
        dl = fminf(dl, __shfl_xor(dl, off, 64));
        dh = fmaxf(dh, __shfl_xor(dh, off, 64));
    }
    if ((p & 63) == 0) { mmx[wv] = dl; mmx[6 + wv] = dh; }
    __syncthreads();
    if (p == 0) {
        float mn = mmx[0], mx = mmx[6];
        #pragma unroll
        for (int w = 1; w < 6; ++w) {
            mn = fminf(mn, mmx[w]);
            mx = fmaxf(mx, mmx[6 + w]);
        }
        int S = (int)(383.0f / (mx - mn + 1.0f));
        if (S < 1) S = 1;
        sprm[0] = mn;
        sprm[1] = (float)S;
    }
    __syncthreads();
    const float dmin   = sprm[0];
    const float scaleF = sprm[1];
    const int   S      = (int)scaleF;

    // P3a: histogram (self clamps to bin 0; rank strictness excludes it)
    int q = (int)((d - dmin) * scaleF);
    if (q < 0) q = 0;
    if (q > NBIN - 1) q = NBIN - 1;
    atomicAdd(&hist[q], 1u);
    const int4 r4 = *reinterpret_cast<const int4*>(rank + p * 4);
    const unsigned rpk = (unsigned)r4.x | ((unsigned)r4.y << 8) |
                         ((unsigned)r4.z << 16) | ((unsigned)r4.w << 24);
    __syncthreads();

    // P3b: exclusive prefix over 384 bins
    const unsigned h = hist[p];
    unsigned inc = h;
    #pragma unroll
    for (int s = 1; s < 64; s <<= 1) {
        const unsigned o = __shfl_up(inc, s, 64);
        if ((p & 63) >= s) inc += o;
    }
    if ((p & 63) == 63) wtot[wv] = inc;
    __syncthreads();
    unsigned woff = 0;
    for (int w = 0; w < wv; ++w) woff += wtot[w];
    const unsigned excl = woff + inc - h;
    offs[p] = excl;
    curs[p] = excl;
    if (p == NBIN - 1) offs[NBIN] = excl + h;   // == NB
    __syncthreads();

    // P3c: counting scatter into d-grouped order
    const unsigned pos = atomicAdd(&curs[q], 1u);
    srk[pos] = rpk;
    __syncthreads();

    // P4: ballot cumulative-rank masks
    const unsigned rsv = srk[p];
    #pragma unroll
    for (int t = 0; t < 4; ++t) {
        const unsigned rt = (rsv >> (8 * t)) & 0xFFu;
        #pragma unroll
        for (int w = 0; w < 4; ++w) {
            const unsigned long long m = __ballot(rt <= (unsigned)w);
            if ((p & 63) == 0) cm[wv][t * 4 + w] = m;
        }
    }
    __syncthreads();
    if (p < 16) {
        unsigned c = 0;
        #pragma unroll
        for (int w2 = 0; w2 < 6; ++w2) {
            cumtab[w2][p] = c;
            c += (unsigned)__popcll(cm[w2][p]);
        }
        cumtab[6][p] = c;                       // grand totals
    }
    __syncthreads();

    // P5: contribution (both roles)
    const float thr = d + 1.0f;
    const int jidx = (q + S > NBIN) ? NBIN : (q + S);
    const int kidx = (q - S + 1 < 0) ? 0 : (q - S + 1);
    const unsigned P = offs[jidx];     // j-role partners: pos <  P
    const unsigned L = offs[kidx];     // k-role partners: pos >= L
    const int Pwv = (int)(P >> 6), Lwv = (int)(L >> 6);
    const unsigned long long Pmask = (1ull << (P & 63)) - 1ull;
    const unsigned long long Lmask = (1ull << (L & 63)) - 1ull;

    const int4 ri4 = *reinterpret_cast<const int4*>(rank + bi * 4);
    const unsigned rip = (unsigned)ri4.x | ((unsigned)ri4.y << 8) |
                         ((unsigned)ri4.z << 16) | ((unsigned)ri4.w << 24);

    float jacc = 0.f, kacc = 0.f;
    #pragma unroll
    for (int t = 0; t < 4; ++t) {
        const int ri = (int)((rip >> (8 * t)) & 0xFFu);
        const int ro = (int)((rpk >> (8 * t)) & 0xFFu);
        const float wt = wfl[t];
        if (ro > 0 && ro < ri) {                       // j-role
            const int w = t * 4 + (ro - 1);
            const unsigned N = cumtab[Pwv][w] +
                               (unsigned)__popcll(cm[Pwv][w] & Pmask);
            jacc += wt * (float)N;
        }
        if (ro + 1 < ri) {                             // k-role
            const int wh = t * 4 + (ri - 1);
            const int wl = t * 4 + ro;
            const unsigned cLh = cumtab[Lwv][wh] +
                                 (unsigned)__popcll(cm[Lwv][wh] & Lmask);
            const unsigned cLl = cumtab[Lwv][wl] +
                                 (unsigned)__popcll(cm[Lwv][wl] & Lmask);
            const unsigned C = (cumtab[6][wh] - cLh) - (cumtab[6][wl] - cLl);
            kacc += wt * (float)C;
        }
    }
    float contrib = jacc * thr - kacc * d;

    // block reduction
    #pragma unroll
    for (int off = 32; off > 0; off >>= 1)
        contrib += __shfl_down(contrib, off);
    if ((p & 63) == 0) red[wv] = contrib;
    __syncthreads();
    if (p == 0) {
        float s = 0.f;
        #pragma unroll
        for (int w = 0; w < 6; ++w) s += red[w];
        __hip_atomic_store(&partial[bi], __float_as_uint(s),
                           __ATOMIC_RELEASE, __HIP_MEMORY_SCOPE_AGENT);
    }

    // designated block: spin past sentinels (independent slots), fold -> out
    if (bi == NB - 1) {
        __syncthreads();                 // red[] reuse: prior reads complete
        unsigned v;
        do {
            v = __hip_atomic_load(&partial[p], __ATOMIC_ACQUIRE,
                                  __HIP_MEMORY_SCOPE_AGENT);
        } while (v == SENT);
        float val = __uint_as_float(v);
        #pragma unroll
        for (int off = 32; off > 0; off >>= 1)
            val += __shfl_down(val, off);
        if ((p & 63) == 0) red[wv] = val;
        __syncthreads();
        if (p == 0) {
            float s = 0.f;
            #pragma unroll
            for (int w = 0; w < 6; ++w) s += red[w];
            out[0] = s;
        }
    }
}

extern "C" void kernel_launch(void* const* d_in, const int* in_sizes, int n_in,
                              void* d_out, int out_size, void* d_ws, size_t ws_size,
                              hipStream_t stream)
{
    (void)in_sizes; (void)n_in; (void)out_size; (void)ws_size;
    const float* emb  = (const float*)d_in[0];
    const float* tw   = (const float*)d_in[1];
    const int*   rank = (const int*)d_in[2];
    float* ws  = (float*)d_ws;
    float* out = (float*)d_out;

    prep_kernel<<<96, 256, 0, stream>>>(emb, tw, rank, ws);
    loss_kernel<<<NB, NB, 0, stream>>>(
        emb, reinterpret_cast<const uint2*>(ws + ETP_OFF), rank,
        ws + WF_OFF, reinterpret_cast<unsigned*>(ws + PART_OFF), out);
}